// Round 13
// baseline (261.092 us; speedup 1.0000x reference)
//
#include <hip/hip_runtime.h>
#include <hip/hip_bf16.h>

#define NTOK 16384
#define HID 7168
#define NEXP 256
#define TOPK 8

#define BK 64                  // k per phase
#define NPH (HID / BK)         // 112

typedef __bf16 bf16x8 __attribute__((ext_vector_type(8)));
typedef float  f32x16 __attribute__((ext_vector_type(16)));

typedef __attribute__((address_space(1))) const unsigned char ga_t;
typedef __attribute__((address_space(3))) unsigned char la_t;

// Weights, MFMA-fragment-linear (same layout as R12, proven):
// uint4 idx = ((p8*8 + g)*8 + ks)*64 + lane  holds
// B[e = g*32 + (lane&31)][k = p8*128 + ks*16 + (lane>>5)*8 .. +8]
__device__ __align__(16) unsigned short g_wb[NEXP * HID];

__device__ __forceinline__ unsigned int f2bfb(float x) {
    unsigned int u = __float_as_uint(x);
    return (u + 0x7fffu + ((u >> 16) & 1u)) >> 16;
}
__device__ __forceinline__ uint4 pk4(float4 p, float4 q) {
    uint4 u;
    u.x = f2bfb(p.x) | (f2bfb(p.y) << 16);
    u.y = f2bfb(p.z) | (f2bfb(p.w) << 16);
    u.z = f2bfb(q.x) | (f2bfb(q.y) << 16);
    u.w = f2bfb(q.z) | (f2bfb(q.w) << 16);
    return u;
}
__device__ __forceinline__ bf16x8 asbf8(uint4 u) {
    union { uint4 a; bf16x8 b; } c; c.a = u; return c.b;
}
__device__ __forceinline__ void gll16(const void* g, void* l) {
    __builtin_amdgcn_global_load_lds((ga_t*)g, (la_t*)l, 16, 0, 0);
}
__device__ __forceinline__ bf16x8 cvt8(float4 p, float4 q) {
    union { bf16x8 v; __hip_bfloat162 h[4]; } c;
    c.h[0] = __float22bfloat162_rn(make_float2(p.x, p.y));
    c.h[1] = __float22bfloat162_rn(make_float2(p.z, p.w));
    c.h[2] = __float22bfloat162_rn(make_float2(q.x, q.y));
    c.h[3] = __float22bfloat162_rn(make_float2(q.z, q.w));
    return c.v;
}

__global__ void wconv_frag(const float* __restrict__ wt) {
    const int tid = blockIdx.x * 256 + threadIdx.x;
    const int l  = tid & 63;
    const int ks = (tid >> 6) & 7;
    const int g  = (tid >> 9) & 7;
    const int p  = tid >> 12;
    const int e  = g * 32 + (l & 31);
    const int kb = p * 128 + ks * 16 + ((l >> 5) << 3);
    const float4* s = (const float4*)(wt + (size_t)e * HID + kb);
    ((uint4*)g_wb)[tid] = pk4(s[0], s[1]);
}

__global__ void moe_rows(float* __restrict__ ob) {
    const int q = blockIdx.x * 256 + threadIdx.x;
    ob[262144 + q] = (float)((q & 7) * NTOK + (q >> 3));
}

// Block: 256 thr = 4 waves. Wave w: tokens [blk*64 + (w>>1)*32, +32), experts
// [(w&1)*128, +128). K-loop is barrier-free: wave-private LDS A (4 slots x 8KB),
// reg-resident B. LDS total 128 KB; epilogue aliases logits [64][257] f32.
__global__ __launch_bounds__(256) void moe_gate_v13(
    const float* __restrict__ hs,
    float* __restrict__ ob)
{
    __shared__ __align__(16) char smem[131072];

    const int tid   = threadIdx.x;
    const int lane  = tid & 63;
    const int w     = tid >> 6;        // 0..3
    const int tg    = w >> 1;          // token group
    const int h     = w & 1;           // expert half
    const int tw0   = blockIdx.x * 64 + tg * 32;
    char* const wbuf = smem + w * 32768;

    // ---- A gll sources (pre-swizzled): instr i covers rows 4i..4i+3 ----
    const char* aSrc[4];
    #pragma unroll
    for (int i = 0; i < 4; ++i) {
        const int row = 4 * i + (lane >> 4);              // 0..15
        const int cs  = (((lane & 15) << 4) ^ ((row & 15) << 4));
        aSrc[i] = (const char*)hs + (size_t)(tw0 + row) * (HID * 4) + cs;
    }
    // rows 16..31: +16*HID*4; (row&15) unchanged so swizzle identical
    const size_t AHI = (size_t)16 * HID * 4;

    // ---- B base (fragment-linear, coalesced): + phase-byte + j*8192 + ks*1024 ----
    const char* const bB = (const char*)g_wb + h * 32768 + lane * 16;

    // ---- A fragment read geometry (256-B rows, XOR swizzle) ----
    const int khalf = lane >> 5;
    const int abase = (lane & 31) * 256;
    const int aswz  = ((lane & 31) & 15) << 4;

    f32x16 acc0 = {}, acc1 = {}, acc2 = {}, acc3 = {};
    uint4 b0[16], b1[16];   // B double-set; all indices static after unroll

#define ISSUE_A(Q, SLOT)                                                      \
    do {                                                                      \
        char* dst = wbuf + ((SLOT) << 13);                                    \
        _Pragma("unroll")                                                     \
        for (int i = 0; i < 4; ++i)                                           \
            gll16(aSrc[i] + (size_t)(Q) * 256, dst + i * 1024);               \
        _Pragma("unroll")                                                     \
        for (int i = 0; i < 4; ++i)                                           \
            gll16(aSrc[i] + AHI + (size_t)(Q) * 256, dst + 4096 + i * 1024);  \
    } while (0)

#define ISSUE_B(BP, SET)                                                      \
    do {                                                                      \
        _Pragma("unroll")                                                     \
        for (int j = 0; j < 4; ++j)                                           \
            _Pragma("unroll")                                                 \
            for (int ks = 0; ks < 4; ++ks)                                    \
                SET[j * 4 + ks] = *(const uint4*)((BP) + j * 8192 + ks * 1024); \
    } while (0)

#define COMPUTE(BUFP, SET)                                                    \
    do {                                                                      \
        _Pragma("unroll")                                                     \
        for (int ks = 0; ks < 4; ++ks) {                                      \
            const int o = ks * 64 + khalf * 32;                               \
            float4 a0 = *(const float4*)((BUFP) + abase + ((o     ) ^ aswz)); \
            float4 a1 = *(const float4*)((BUFP) + abase + ((o + 16) ^ aswz)); \
            bf16x8 a = cvt8(a0, a1);                                          \
            acc0 = __builtin_amdgcn_mfma_f32_32x32x16_bf16(a, asbf8(SET[     ks]), acc0, 0, 0, 0); \
            acc1 = __builtin_amdgcn_mfma_f32_32x32x16_bf16(a, asbf8(SET[ 4 + ks]), acc1, 0, 0, 0); \
            acc2 = __builtin_amdgcn_mfma_f32_32x32x16_bf16(a, asbf8(SET[ 8 + ks]), acc2, 0, 0, 0); \
            acc3 = __builtin_amdgcn_mfma_f32_32x32x16_bf16(a, asbf8(SET[12 + ks]), acc3, 0, 0, 0); \
        }                                                                     \
    } while (0)

#define VMW(N)                                                                \
    do {                                                                      \
        asm volatile("s_waitcnt vmcnt(" #N ")" ::: "memory");                 \
        __builtin_amdgcn_sched_barrier(0);                                    \
    } while (0)

    // ---- prologue: FIFO [A(0), B(0), A(1)] = 32 outstanding ----
    ISSUE_A(0, 0);
    ISSUE_B(bB, b0);
    ISSUE_A(1, 1);

    // ---- main loop: q = p (even, set0) and p+1 (odd, set1); no barriers ----
    const char* bpi = bB;                 // = bB + (p>>1)*65536
    for (int p = 0; p < 108; p += 2) {
        // phase q=p: waits A(p),B(p); keeps A(p+1),B(p+1),A(p+2) in flight
        ISSUE_B(bpi + 4096, b1);          // B(p+1)
        ISSUE_A(p + 2, ((p + 2) & 3));
        VMW(32);
        COMPUTE(wbuf + ((p & 3) << 13), b0);
        // phase q=p+1
        ISSUE_B(bpi + 65536, b0);         // B(p+2)
        ISSUE_A(p + 3, ((p + 3) & 3));
        VMW(32);
        COMPUTE(wbuf + (((p + 1) & 3) << 13), b1);
        bpi += 65536;
    }
    // peel q=108..111  (bpi = bB + 54*65536)
    ISSUE_B(bpi + 4096, b1);              // B(109)
    ISSUE_A(110, 2);
    VMW(32);
    COMPUTE(wbuf + (0 << 13), b0);        // q=108
    ISSUE_B(bpi + 65536, b0);             // B(110)
    ISSUE_A(111, 3);
    VMW(32);
    COMPUTE(wbuf + (1 << 13), b1);        // q=109
    ISSUE_B(bpi + 65536 + 4096, b1);      // B(111)
    VMW(24);
    COMPUTE(wbuf + (2 << 13), b0);        // q=110
    VMW(0);
    COMPUTE(wbuf + (3 << 13), b1);        // q=111

    __syncthreads();                      // only block-wide sync: epilogue begins

    // ---- epilogue: dump logits to LDS [64][257] f32 ----
    float* ll = (float*)smem;
    {
        const int rb = 4 * khalf;
        #pragma unroll
        for (int j = 0; j < 4; ++j) {
            const int ec = h * 128 + j * 32 + (lane & 31);
            #pragma unroll
            for (int r = 0; r < 16; ++r) {
                const int tok = tg * 32 + (r & 3) + 8 * (r >> 2) + rb;
                const float v = (j == 0) ? acc0[r] : (j == 1) ? acc1[r]
                              : (j == 2) ? acc2[r] : acc3[r];
                ll[tok * 257 + ec] = v;
            }
        }
    }
    __syncthreads();

    if (tid < 64) {
        const float* lr = ll + tid * 257;
        float bv[TOPK]; int bi8[TOPK];
        #pragma unroll
        for (int k = 0; k < TOPK; ++k) { bv[k] = -1e30f; bi8[k] = 0; }
        for (int e = 0; e < NEXP; ++e) {
            const float v = lr[e];
            if (v > bv[TOPK - 1]) {
                int k = TOPK - 1;
                while (k > 0 && v > bv[k - 1]) {
                    bv[k] = bv[k - 1]; bi8[k] = bi8[k - 1]; --k;
                }
                bv[k] = v; bi8[k] = e;      // strict > : ties keep lower idx
            }
        }
        float ev[TOPK], ssum = 0.f;
        #pragma unroll
        for (int r = 0; r < TOPK; ++r) { ev[r] = expf(bv[r] - bv[0]); ssum += ev[r]; }
        const float inv = 1.0f / ssum;

        const int tgl = blockIdx.x * 64 + tid;
        #pragma unroll
        for (int r = 0; r < TOPK; ++r) {
            ob[(size_t)tgl * TOPK + r]          = (float)bi8[r];   // idx
            ob[131072 + (size_t)tgl * TOPK + r] = ev[r] * inv;     // weight
        }
    }
#undef ISSUE_A
#undef ISSUE_B
#undef COMPUTE
#undef VMW
}

extern "C" void kernel_launch(void* const* d_in, const int* in_sizes, int n_in,
                              void* d_out, int out_size, void* d_ws, size_t ws_size,
                              hipStream_t stream) {
    const float* hs = (const float*)d_in[0];   // [16384, 7168] f32
    const float* wt = (const float*)d_in[1];   // [256, 7168] f32
    float* ob = (float*)d_out;                 // f32[393216]: idx | weight | row

    wconv_frag<<<dim3(NEXP * HID / 8 / 256), dim3(256), 0, stream>>>(wt);
    moe_gate_v13<<<dim3(NTOK / 64), dim3(256), 0, stream>>>(hs, ob);
    moe_rows<<<dim3(512), dim3(256), 0, stream>>>(ob);
}